// Round 9
// baseline (135.701 us; speedup 1.0000x reference)
//
#include <hip/hip_runtime.h>
#include <hip/hip_bf16.h>

// SpatialAttention: out[b,i,j] = softmax_j( sum_c w3[c] * tanh(x1[b,i,c] + x2[b,j,c]) )
// x1 = x@W1^T, x2 = x@W2^T.  B=4, N=1024, C=64.
//
// tanh(s) = 1 - 2/(exp2(K2*s)+1); exp2 factorizes: exp2(K2*(x1+x2)) = e1*e2,
// precomputed in proj (each clamped to 2^15).
// att = sum(w3) - 2 * sum_c w3[c] * rcp(fma(e1,e2,1)); paired rcp over i-pair.
//
// R9 theory: VALU-busy time is invariant ~22 us across R4/R6/R8; dur is pure
// stall exposure.  Grid caps occupancy at 4 waves/SIMD (1024 blocks x 4 waves,
// 4 blocks/CU) so VGPR<=128 is FREE: __launch_bounds__(256,4) unlocks it.
// J=4 j/thread -> each e1 ds_read_b128 feeds 8 step2 (LDS 6.4us/CU << VALU
// 17us).  e2 double-buffered one full iteration ahead (~640cyc body >> L2
// latency).  w3 in LDS so in-loop lgkm ops are DS-only (in-order, fine-grained
// lgkmcnt; R7 showed s_load mixing forces lgkmcnt(0) serialization).

#define BATCH 4
#define NN    1024
#define CC    64
#define TI    4              // rows i per attn block
#define BLK   256
#define J4    4              // j's per thread
#define PP    65             // padded pitch for transposed W in LDS
#define PROWS 16             // rows per proj block

__device__ __forceinline__ float fast_exp2(float x) {
#if __has_builtin(__builtin_amdgcn_exp2f)
    return __builtin_amdgcn_exp2f(x);
#else
    return exp2f(x);
#endif
}
__device__ __forceinline__ float fast_rcp(float x) {
#if __has_builtin(__builtin_amdgcn_rcpf)
    return __builtin_amdgcn_rcpf(x);
#else
    return 1.0f / x;
#endif
}

// ---------------- Kernel 1: projections -> exp2 factors ---------------------
__global__ __launch_bounds__(256) void proj_kernel(
    const float* __restrict__ x, const float* __restrict__ W1,
    const float* __restrict__ W2, float* __restrict__ e1p,
    float* __restrict__ e2p) {
    __shared__ float w1t[CC * PP];        // [c][d] transposed, 16.25 KB
    __shared__ float w2t[CC * PP];
    __shared__ float xs[PROWS * CC];      // [r][c] straight, 4 KB

    const int tid = threadIdx.x;
    const int r0  = blockIdx.x * PROWS;
    {   // W: coalesced load + transpose into LDS
        const float4* __restrict__ W1v = (const float4*)W1;
        const float4* __restrict__ W2v = (const float4*)W2;
#pragma unroll
        for (int k = 0; k < 4; ++k) {
            const int fi = k * 256 + tid;      // float4 index in [0,1024)
            const int r  = fi >> 4;            // row d
            const int c4 = (fi & 15) * 4;      // col c base
            float4 a = W1v[fi], b = W2v[fi];
            w1t[(c4 + 0) * PP + r] = a.x; w1t[(c4 + 1) * PP + r] = a.y;
            w1t[(c4 + 2) * PP + r] = a.z; w1t[(c4 + 3) * PP + r] = a.w;
            w2t[(c4 + 0) * PP + r] = b.x; w2t[(c4 + 1) * PP + r] = b.y;
            w2t[(c4 + 2) * PP + r] = b.z; w2t[(c4 + 3) * PP + r] = b.w;
        }
        // x tile: coalesced, conflict-free
        const int rr = tid >> 6, c = tid & 63;
#pragma unroll
        for (int k = 0; k < 4; ++k) {
            const int r = k * 4 + rr;
            xs[r * CC + c] = x[(size_t)(r0 + r) * CC + c];
        }
    }
    __syncthreads();

    const int w    = tid >> 6;
    const int lane = tid & 63;
    const int rb   = w * 4;               // this wave's 4 rows (in-block)

    float a1[4] = {0.f, 0.f, 0.f, 0.f};
    float a2[4] = {0.f, 0.f, 0.f, 0.f};
#pragma unroll
    for (int c = 0; c < CC; ++c) {
        const float w1v = w1t[c * PP + lane];
        const float w2v = w2t[c * PP + lane];
        const float x0 = xs[(rb + 0) * CC + c];   // broadcast reads
        const float x1 = xs[(rb + 1) * CC + c];
        const float x2v = xs[(rb + 2) * CC + c];
        const float x3 = xs[(rb + 3) * CC + c];
        a1[0] = fmaf(x0, w1v, a1[0]);  a2[0] = fmaf(x0, w2v, a2[0]);
        a1[1] = fmaf(x1, w1v, a1[1]);  a2[1] = fmaf(x1, w2v, a2[1]);
        a1[2] = fmaf(x2v, w1v, a1[2]); a2[2] = fmaf(x2v, w2v, a2[2]);
        a1[3] = fmaf(x3, w1v, a1[3]);  a2[3] = fmaf(x3, w2v, a2[3]);
    }
    const float K2 = 2.8853900817779268f;  // 2*log2(e)
#pragma unroll
    for (int rr = 0; rr < 4; ++rr) {
        const size_t r = (size_t)(r0 + rb + rr);
        e1p[r * CC + lane] = fast_exp2(fminf(a1[rr] * K2, 15.f));
        e2p[r * CC + lane] = fast_exp2(fminf(a2[rr] * K2, 15.f));
    }
}

// ---------------- Kernel 2: fused att + softmax -----------------------------
// paired reciprocal for one i-pair, one j (2 elements):
__device__ __forceinline__ void step2(float e1a, float e1b, float e2,
                                      float wc, float2& acc) {
    float da = fmaf(e1a, e2, 1.f);
    float db = fmaf(e1b, e2, 1.f);
    float r  = fast_rcp(da * db);
    float t  = wc * r;
    acc.x = fmaf(db, t, acc.x);   // wc / da
    acc.y = fmaf(da, t, acc.y);   // wc / db
}

__global__ __launch_bounds__(BLK, 4) void attn_kernel(
    const float* __restrict__ e1p, const float* __restrict__ e2p,
    const float* __restrict__ w3, float* __restrict__ out) {
    __shared__ float e1t[CC * TI];          // [c][i] transposed: 1 KB
    __shared__ float w3s[CC];               // 256 B
    __shared__ float att_lds[TI * NN];      // 16 KB

    const int tid = threadIdx.x;
    const int bi  = blockIdx.x;             // 1024 blocks
    const int b   = bi >> 8;                // 256 blocks per batch
    const int i0  = (bi & 255) * TI;

    {   // stage e1 tile transposed (tid exactly covers CC*TI=256) + w3
        const int ii = tid >> 6, c = tid & 63;
        e1t[c * TI + ii] = e1p[(size_t)((b << 10) + i0 + ii) * CC + c];
        if (tid < CC) w3s[tid] = w3[tid];
    }
    __syncthreads();

    // sum(w3) via uniform scalar loads (outside the hot loop)
    const float4* __restrict__ w3q = (const float4*)w3;
    float sumw3 = 0.f;
#pragma unroll
    for (int q = 0; q < 16; ++q) {
        float4 t = w3q[q];
        sumw3 += (t.x + t.y) + (t.z + t.w);
    }

    const float* __restrict__ e2b = e2p + ((size_t)b << 10) * CC;
    const float4* __restrict__ row0 = (const float4*)(e2b + (size_t)(tid          ) * CC);
    const float4* __restrict__ row1 = (const float4*)(e2b + (size_t)(tid + 1 * BLK) * CC);
    const float4* __restrict__ row2 = (const float4*)(e2b + (size_t)(tid + 2 * BLK) * CC);
    const float4* __restrict__ row3 = (const float4*)(e2b + (size_t)(tid + 3 * BLK) * CC);
    const float4* e1t4 = (const float4*)e1t;   // [c] -> 4 i's (broadcast)
    const float4* w3s4 = (const float4*)w3s;

    // accumulators: [j][i-pair]
    float2 a0A = {0.f,0.f}, a0B = {0.f,0.f};
    float2 a1A = {0.f,0.f}, a1B = {0.f,0.f};
    float2 a2A = {0.f,0.f}, a2B = {0.f,0.f};
    float2 a3A = {0.f,0.f}, a3B = {0.f,0.f};

    // double-buffered e2: current quad preloaded
    float4 c0 = row0[0], c1 = row1[0], c2 = row2[0], c3 = row3[0];

#pragma unroll 1
    for (int ct = 0; ct < 16; ++ct) {          // 16 tiles of 4 c
        const int nx = (ct < 15) ? ct + 1 : 15;
        float4 n0 = row0[nx], n1 = row1[nx], n2 = row2[nx], n3 = row3[nx];

        const float4 wv = w3s4[ct];            // DS read (in-order lgkm)
        const float ca0[4] = {c0.x, c0.y, c0.z, c0.w};
        const float ca1[4] = {c1.x, c1.y, c1.z, c1.w};
        const float ca2[4] = {c2.x, c2.y, c2.z, c2.w};
        const float ca3[4] = {c3.x, c3.y, c3.z, c3.w};
        const float wa[4]  = {wv.x, wv.y, wv.z, wv.w};
#pragma unroll
        for (int m = 0; m < 4; ++m) {
            const float4 ev = e1t4[ct * 4 + m];    // ONE ds_read_b128 ...
            step2(ev.x, ev.y, ca0[m], wa[m], a0A); // ... feeds 8 step2
            step2(ev.z, ev.w, ca0[m], wa[m], a0B);
            step2(ev.x, ev.y, ca1[m], wa[m], a1A);
            step2(ev.z, ev.w, ca1[m], wa[m], a1B);
            step2(ev.x, ev.y, ca2[m], wa[m], a2A);
            step2(ev.z, ev.w, ca2[m], wa[m], a2B);
            step2(ev.x, ev.y, ca3[m], wa[m], a3A);
            step2(ev.z, ev.w, ca3[m], wa[m], a3B);
        }
        c0 = n0; c1 = n1; c2 = n2; c3 = n3;
    }

    {
        const int j0 = tid;
        att_lds[0 * NN + j0 + 0 * BLK] = fmaf(-2.f, a0A.x, sumw3);
        att_lds[1 * NN + j0 + 0 * BLK] = fmaf(-2.f, a0A.y, sumw3);
        att_lds[2 * NN + j0 + 0 * BLK] = fmaf(-2.f, a0B.x, sumw3);
        att_lds[3 * NN + j0 + 0 * BLK] = fmaf(-2.f, a0B.y, sumw3);
        att_lds[0 * NN + j0 + 1 * BLK] = fmaf(-2.f, a1A.x, sumw3);
        att_lds[1 * NN + j0 + 1 * BLK] = fmaf(-2.f, a1A.y, sumw3);
        att_lds[2 * NN + j0 + 1 * BLK] = fmaf(-2.f, a1B.x, sumw3);
        att_lds[3 * NN + j0 + 1 * BLK] = fmaf(-2.f, a1B.y, sumw3);
        att_lds[0 * NN + j0 + 2 * BLK] = fmaf(-2.f, a2A.x, sumw3);
        att_lds[1 * NN + j0 + 2 * BLK] = fmaf(-2.f, a2A.y, sumw3);
        att_lds[2 * NN + j0 + 2 * BLK] = fmaf(-2.f, a2B.x, sumw3);
        att_lds[3 * NN + j0 + 2 * BLK] = fmaf(-2.f, a2B.y, sumw3);
        att_lds[0 * NN + j0 + 3 * BLK] = fmaf(-2.f, a3A.x, sumw3);
        att_lds[1 * NN + j0 + 3 * BLK] = fmaf(-2.f, a3A.y, sumw3);
        att_lds[2 * NN + j0 + 3 * BLK] = fmaf(-2.f, a3B.x, sumw3);
        att_lds[3 * NN + j0 + 3 * BLK] = fmaf(-2.f, a3B.y, sumw3);
    }
    __syncthreads();

    // epilogue: wave w softmaxes row i0+w over j (4 waves = TI rows)
    {
        const int w    = tid >> 6;
        const int lane = tid & 63;
        float v[16];
        float m = -3.4e38f;
#pragma unroll
        for (int k = 0; k < 16; ++k) {
            v[k] = att_lds[w * NN + k * 64 + lane];
            m = fmaxf(m, v[k]);
        }
#pragma unroll
        for (int off = 32; off >= 1; off >>= 1)
            m = fmaxf(m, __shfl_xor(m, off));
        const float L2E = 1.4426950408889634f;
        float s = 0.f;
#pragma unroll
        for (int k = 0; k < 16; ++k) {
            v[k] = fast_exp2((v[k] - m) * L2E);
            s += v[k];
        }
#pragma unroll
        for (int off = 32; off >= 1; off >>= 1)
            s += __shfl_xor(s, off);
        const float rs = fast_rcp(s);
        float* __restrict__ orow = out + (((size_t)(b << 10) + (i0 + w)) << 10);
#pragma unroll
        for (int k = 0; k < 16; ++k) orow[k * 64 + lane] = v[k] * rs;
    }
}

extern "C" void kernel_launch(void* const* d_in, const int* in_sizes, int n_in,
                              void* d_out, int out_size, void* d_ws, size_t ws_size,
                              hipStream_t stream) {
    const float* x  = (const float*)d_in[0];
    const float* W1 = (const float*)d_in[1];
    const float* W2 = (const float*)d_in[2];
    const float* w3 = (const float*)d_in[3];
    float* outp = (float*)d_out;

    float* e1p = (float*)d_ws;                       // 4096*64 fp32 = 1 MB
    float* e2p = e1p + (size_t)BATCH * NN * CC;      // second 1 MB

    proj_kernel<<<dim3(BATCH * NN / PROWS), dim3(256), 0, stream>>>(x, W1, W2, e1p, e2p);
    attn_kernel<<<dim3(BATCH * NN / TI), dim3(BLK), 0, stream>>>(e1p, e2p, w3, outp);
}

// Round 10
// 133.582 us; speedup vs baseline: 1.0159x; 1.0159x over previous
//
#include <hip/hip_runtime.h>
#include <hip/hip_bf16.h>

// SpatialAttention: out[b,i,j] = softmax_j( sum_c w3[c] * tanh(x1[b,i,c] + x2[b,j,c]) )
// x1 = x@W1^T, x2 = x@W2^T.  B=4, N=1024, C=64.
//
// tanh(s) = 1 - 2/(exp2(K2*s)+1); exp2(K2*(x1+x2)) = e1*e2 precomputed in
// proj (each clamped to 2^15).  att = sum(w3) - 2*sum_c w3[c]*rcp(fma(e1,e2,1)).
// Paired rcp over the i-pair: r=rcp(da*db); t=wc*r; acc += (db,da)*t.
//
// R10 = R6 (best, 42.7us) + three surgical deltas, designed to fit the
// allocator's hard 64-VGPR ceiling (observed across 10 rounds):
//  (1) w3 in LDS: R6's in-loop s_load(w3) mixed SMEM+DS in lgkmcnt ->
//      lgkmcnt(0) serialization before every e1t use (R7's lesson; R6 had it
//      too).  Now the hot loop is DS-only -> fine-grained lgkmcnt(N).
//  (2) merged j-chunks (j, j+512 one pass): each e1 ds_read_b128 feeds
//      4 step2 -> LDS ~15cyc < VALU ~40cyc per c per CU (R6 read e1t twice,
//      LDS-bound).  Scalar float4 components only — NO local arrays (R8's
//      ea[4] arrays triggered a 32-VGPR allocator bin).
//  (3) 1-deep e2 prefetch (2 float4 = 8 regs): covers ~200cyc L2 latency
//      with ~320cyc of per-iteration VALU.
// Live state ~50 VGPR: 8 acc + 8 cur + 8 next + 4 ev + 4 wq + addr/misc.

#define BATCH 4
#define NN    1024
#define CC    64
#define TI    4              // rows i per attn block
#define BLK   512
#define PP    65             // padded pitch for transposed W in LDS
#define PROWS 16             // rows per proj block

__device__ __forceinline__ float fast_exp2(float x) {
#if __has_builtin(__builtin_amdgcn_exp2f)
    return __builtin_amdgcn_exp2f(x);
#else
    return exp2f(x);
#endif
}
__device__ __forceinline__ float fast_rcp(float x) {
#if __has_builtin(__builtin_amdgcn_rcpf)
    return __builtin_amdgcn_rcpf(x);
#else
    return 1.0f / x;
#endif
}

// ---------------- Kernel 1: projections -> exp2 factors ---------------------
__global__ __launch_bounds__(256) void proj_kernel(
    const float* __restrict__ x, const float* __restrict__ W1,
    const float* __restrict__ W2, float* __restrict__ e1p,
    float* __restrict__ e2p) {
    __shared__ float w1t[CC * PP];        // [c][d] transposed, 16.25 KB
    __shared__ float w2t[CC * PP];
    __shared__ float xs[PROWS * CC];      // [r][c] straight, 4 KB

    const int tid = threadIdx.x;
    const int r0  = blockIdx.x * PROWS;
    {   // W: coalesced load + transpose into LDS
        const float4* __restrict__ W1v = (const float4*)W1;
        const float4* __restrict__ W2v = (const float4*)W2;
#pragma unroll
        for (int k = 0; k < 4; ++k) {
            const int fi = k * 256 + tid;      // float4 index in [0,1024)
            const int r  = fi >> 4;            // row d
            const int c4 = (fi & 15) * 4;      // col c base
            float4 a = W1v[fi], b = W2v[fi];
            w1t[(c4 + 0) * PP + r] = a.x; w1t[(c4 + 1) * PP + r] = a.y;
            w1t[(c4 + 2) * PP + r] = a.z; w1t[(c4 + 3) * PP + r] = a.w;
            w2t[(c4 + 0) * PP + r] = b.x; w2t[(c4 + 1) * PP + r] = b.y;
            w2t[(c4 + 2) * PP + r] = b.z; w2t[(c4 + 3) * PP + r] = b.w;
        }
        // x tile: coalesced, conflict-free
        const int rr = tid >> 6, c = tid & 63;
#pragma unroll
        for (int k = 0; k < 4; ++k) {
            const int r = k * 4 + rr;
            xs[r * CC + c] = x[(size_t)(r0 + r) * CC + c];
        }
    }
    __syncthreads();

    const int w    = tid >> 6;
    const int lane = tid & 63;
    const int rb   = w * 4;               // this wave's 4 rows (in-block)

    float a1[4] = {0.f, 0.f, 0.f, 0.f};
    float a2[4] = {0.f, 0.f, 0.f, 0.f};
#pragma unroll
    for (int c = 0; c < CC; ++c) {
        const float w1v = w1t[c * PP + lane];
        const float w2v = w2t[c * PP + lane];
        const float x0 = xs[(rb + 0) * CC + c];   // broadcast reads
        const float x1 = xs[(rb + 1) * CC + c];
        const float x2v = xs[(rb + 2) * CC + c];
        const float x3 = xs[(rb + 3) * CC + c];
        a1[0] = fmaf(x0, w1v, a1[0]);  a2[0] = fmaf(x0, w2v, a2[0]);
        a1[1] = fmaf(x1, w1v, a1[1]);  a2[1] = fmaf(x1, w2v, a2[1]);
        a1[2] = fmaf(x2v, w1v, a1[2]); a2[2] = fmaf(x2v, w2v, a2[2]);
        a1[3] = fmaf(x3, w1v, a1[3]);  a2[3] = fmaf(x3, w2v, a2[3]);
    }
    const float K2 = 2.8853900817779268f;  // 2*log2(e)
#pragma unroll
    for (int rr = 0; rr < 4; ++rr) {
        const size_t r = (size_t)(r0 + rb + rr);
        e1p[r * CC + lane] = fast_exp2(fminf(a1[rr] * K2, 15.f));
        e2p[r * CC + lane] = fast_exp2(fminf(a2[rr] * K2, 15.f));
    }
}

// ---------------- Kernel 2: fused att + softmax -----------------------------
// paired reciprocal for one i-pair, one j (2 elements):
__device__ __forceinline__ void step2(float e1a, float e1b, float e2,
                                      float wc, float2& acc) {
    float da = fmaf(e1a, e2, 1.f);
    float db = fmaf(e1b, e2, 1.f);
    float r  = fast_rcp(da * db);
    float t  = wc * r;
    acc.x = fmaf(db, t, acc.x);   // wc / da
    acc.y = fmaf(da, t, acc.y);   // wc / db
}

__global__ __launch_bounds__(BLK) void attn_kernel(
    const float* __restrict__ e1p, const float* __restrict__ e2p,
    const float* __restrict__ w3, float* __restrict__ out) {
    __shared__ float e1t[CC * TI];          // [c][i] transposed: 1 KB
    __shared__ float w3s[CC];               // 256 B
    __shared__ float att_lds[TI * NN];      // 16 KB

    const int tid = threadIdx.x;
    const int bi  = blockIdx.x;             // 1024 blocks
    const int b   = bi >> 8;                // 256 blocks per batch
    const int i0  = (bi & 255) * TI;

    if (tid < CC * TI) {                    // stage e1 tile transposed
        const int ii = tid >> 6, c = tid & 63;
        e1t[c * TI + ii] = e1p[(size_t)((b << 10) + i0 + ii) * CC + c];
    } else if (tid < CC * TI + CC) {        // stage w3
        w3s[tid - CC * TI] = w3[tid - CC * TI];
    }
    __syncthreads();

    // sum(w3) via uniform scalar loads (outside the hot loop: SMEM ok here)
    const float4* __restrict__ w3q = (const float4*)w3;
    float sumw3 = 0.f;
#pragma unroll
    for (int q = 0; q < 16; ++q) {
        float4 t = w3q[q];
        sumw3 += (t.x + t.y) + (t.z + t.w);
    }

    const float* __restrict__ e2b = e2p + ((size_t)b << 10) * CC;
    const float4* __restrict__ rowA = (const float4*)(e2b + (size_t)tid * CC);
    const float4* __restrict__ rowB = rowA + (size_t)BLK * (CC / 4);
    const float4* e1t4 = (const float4*)e1t;   // [c] -> 4 i's (broadcast)
    const float4* w3s4 = (const float4*)w3s;

    float2 aA = {0.f, 0.f}, bA = {0.f, 0.f};   // j0=tid:      i01, i23
    float2 aB = {0.f, 0.f}, bB = {0.f, 0.f};   // j1=tid+512:  i01, i23

    float4 cA = rowA[0];                   // current e2 quads (prefetched)
    float4 cB = rowB[0];

#pragma unroll 1
    for (int ct = 0; ct < 16; ++ct) {      // 16 quads of 4 c
        const int nx = (ct < 15) ? ct + 1 : 15;
        float4 nA = rowA[nx];              // next quads: issued early,
        float4 nB = rowB[nx];              // consumed next iteration

        const float4 wq = w3s4[ct];        // DS (in-order lgkm)

        const float4 e0 = e1t4[ct * 4 + 0];    // one ds_read_b128 ...
        step2(e0.x, e0.y, cA.x, wq.x, aA);     // ... feeds 4 step2
        step2(e0.z, e0.w, cA.x, wq.x, bA);
        step2(e0.x, e0.y, cB.x, wq.x, aB);
        step2(e0.z, e0.w, cB.x, wq.x, bB);

        const float4 e1v = e1t4[ct * 4 + 1];
        step2(e1v.x, e1v.y, cA.y, wq.y, aA);
        step2(e1v.z, e1v.w, cA.y, wq.y, bA);
        step2(e1v.x, e1v.y, cB.y, wq.y, aB);
        step2(e1v.z, e1v.w, cB.y, wq.y, bB);

        const float4 e2v = e1t4[ct * 4 + 2];
        step2(e2v.x, e2v.y, cA.z, wq.z, aA);
        step2(e2v.z, e2v.w, cA.z, wq.z, bA);
        step2(e2v.x, e2v.y, cB.z, wq.z, aB);
        step2(e2v.z, e2v.w, cB.z, wq.z, bB);

        const float4 e3v = e1t4[ct * 4 + 3];
        step2(e3v.x, e3v.y, cA.w, wq.w, aA);
        step2(e3v.z, e3v.w, cA.w, wq.w, bA);
        step2(e3v.x, e3v.y, cB.w, wq.w, aB);
        step2(e3v.z, e3v.w, cB.w, wq.w, bB);

        cA = nA; cB = nB;
    }

    {
        const int j0 = tid, j1 = tid + BLK;
        att_lds[0 * NN + j0] = fmaf(-2.f, aA.x, sumw3);
        att_lds[1 * NN + j0] = fmaf(-2.f, aA.y, sumw3);
        att_lds[2 * NN + j0] = fmaf(-2.f, bA.x, sumw3);
        att_lds[3 * NN + j0] = fmaf(-2.f, bA.y, sumw3);
        att_lds[0 * NN + j1] = fmaf(-2.f, aB.x, sumw3);
        att_lds[1 * NN + j1] = fmaf(-2.f, aB.y, sumw3);
        att_lds[2 * NN + j1] = fmaf(-2.f, bB.x, sumw3);
        att_lds[3 * NN + j1] = fmaf(-2.f, bB.y, sumw3);
    }
    __syncthreads();

    // epilogue: wave w (w < TI) softmaxes row i0+w over j
    {
        const int w    = tid >> 6;
        const int lane = tid & 63;
        if (w < TI) {
            float v[16];
            float m = -3.4e38f;
#pragma unroll
            for (int k = 0; k < 16; ++k) {
                v[k] = att_lds[w * NN + k * 64 + lane];
                m = fmaxf(m, v[k]);
            }
#pragma unroll
            for (int off = 32; off >= 1; off >>= 1)
                m = fmaxf(m, __shfl_xor(m, off));
            const float L2E = 1.4426950408889634f;
            float s = 0.f;
#pragma unroll
            for (int k = 0; k < 16; ++k) {
                v[k] = fast_exp2((v[k] - m) * L2E);
                s += v[k];
            }
#pragma unroll
            for (int off = 32; off >= 1; off >>= 1)
                s += __shfl_xor(s, off);
            const float rs = fast_rcp(s);
            float* __restrict__ orow = out + (((size_t)(b << 10) + (i0 + w)) << 10);
#pragma unroll
            for (int k = 0; k < 16; ++k) orow[k * 64 + lane] = v[k] * rs;
        }
    }
}

extern "C" void kernel_launch(void* const* d_in, const int* in_sizes, int n_in,
                              void* d_out, int out_size, void* d_ws, size_t ws_size,
                              hipStream_t stream) {
    const float* x  = (const float*)d_in[0];
    const float* W1 = (const float*)d_in[1];
    const float* W2 = (const float*)d_in[2];
    const float* w3 = (const float*)d_in[3];
    float* outp = (float*)d_out;

    float* e1p = (float*)d_ws;                       // 4096*64 fp32 = 1 MB
    float* e2p = e1p + (size_t)BATCH * NN * CC;      // second 1 MB

    proj_kernel<<<dim3(BATCH * NN / PROWS), dim3(256), 0, stream>>>(x, W1, W2, e1p, e2p);
    attn_kernel<<<dim3(BATCH * NN / TI), dim3(BLK), 0, stream>>>(e1p, e2p, w3, outp);
}

// Round 11
// 104.604 us; speedup vs baseline: 1.2973x; 1.2770x over previous
//
#include <hip/hip_runtime.h>
#include <hip/hip_bf16.h>

// SpatialAttention: out[b,i,j] = softmax_j( sum_c w3[c] * tanh(x1[b,i,c] + x2[b,j,c]) )
// x1 = x@W1^T, x2 = x@W2^T.  B=4, N=1024, C=64.
//
// tanh(s) = 1 - 2/(exp2(K2*s)+1); exp2(K2*(x1+x2)) = e1*e2 precomputed in
// proj (each clamped to 2^15).  att = sum(w3) - 2*sum_c w3[c]*rcp(fma(e1,e2,1)).
// Paired rcp over the i-pair: r=rcp(da*db); t=wc*r; acc += (db,da)*t.
//
// R11 theory — the 10-round record shows a clean bimodal pattern:
//   VGPR 48-64 kernels -> 42-45us;  VGPR 32 kernels -> 74-77us.
// Occupancy is ANTI-correlated (52% at VGPR=32 vs 30% at 64): more waves with
// no in-flight loads lose to fewer waves with ILP.  Rolled loops let the
// compiler sink prefetches and bin at 32 VGPRs; so: FULLY UNROLL the c-loop
// (straight-line code forces loads live across compute) and set
// __launch_bounds__(256,4) = 128-VGPR budget.  Grid (1024 blocks x 4 waves =
// 4 blocks/CU = 16 waves/CU) caps occupancy at 4 waves/SIMD regardless, so
// VGPR up to 128 is free.  J=4 j's/thread: each e1 ds_read_b128 feeds 8
// step2 (LDS pipe ~1/4 of VALU).  No local arrays (spill trigger in R0/R9).

#define BATCH 4
#define NN    1024
#define CC    64
#define TI    4              // rows i per attn block
#define BLK   256
#define PP    65             // padded pitch for transposed W in LDS
#define PROWS 16             // rows per proj block

__device__ __forceinline__ float fast_exp2(float x) {
#if __has_builtin(__builtin_amdgcn_exp2f)
    return __builtin_amdgcn_exp2f(x);
#else
    return exp2f(x);
#endif
}
__device__ __forceinline__ float fast_rcp(float x) {
#if __has_builtin(__builtin_amdgcn_rcpf)
    return __builtin_amdgcn_rcpf(x);
#else
    return 1.0f / x;
#endif
}

// ---------------- Kernel 1: projections -> exp2 factors ---------------------
__global__ __launch_bounds__(256) void proj_kernel(
    const float* __restrict__ x, const float* __restrict__ W1,
    const float* __restrict__ W2, float* __restrict__ e1p,
    float* __restrict__ e2p) {
    __shared__ float w1t[CC * PP];        // [c][d] transposed, 16.25 KB
    __shared__ float w2t[CC * PP];
    __shared__ float xs[PROWS * CC];      // [r][c] straight, 4 KB

    const int tid = threadIdx.x;
    const int r0  = blockIdx.x * PROWS;
    {   // W: coalesced load + transpose into LDS
        const float4* __restrict__ W1v = (const float4*)W1;
        const float4* __restrict__ W2v = (const float4*)W2;
#pragma unroll
        for (int k = 0; k < 4; ++k) {
            const int fi = k * 256 + tid;      // float4 index in [0,1024)
            const int r  = fi >> 4;            // row d
            const int c4 = (fi & 15) * 4;      // col c base
            float4 a = W1v[fi], b = W2v[fi];
            w1t[(c4 + 0) * PP + r] = a.x; w1t[(c4 + 1) * PP + r] = a.y;
            w1t[(c4 + 2) * PP + r] = a.z; w1t[(c4 + 3) * PP + r] = a.w;
            w2t[(c4 + 0) * PP + r] = b.x; w2t[(c4 + 1) * PP + r] = b.y;
            w2t[(c4 + 2) * PP + r] = b.z; w2t[(c4 + 3) * PP + r] = b.w;
        }
        // x tile: coalesced, conflict-free
        const int rr = tid >> 6, c = tid & 63;
#pragma unroll
        for (int k = 0; k < 4; ++k) {
            const int r = k * 4 + rr;
            xs[r * CC + c] = x[(size_t)(r0 + r) * CC + c];
        }
    }
    __syncthreads();

    const int w    = tid >> 6;
    const int lane = tid & 63;
    const int rb   = w * 4;               // this wave's 4 rows (in-block)

    float a1[4] = {0.f, 0.f, 0.f, 0.f};
    float a2[4] = {0.f, 0.f, 0.f, 0.f};
#pragma unroll
    for (int c = 0; c < CC; ++c) {
        const float w1v = w1t[c * PP + lane];
        const float w2v = w2t[c * PP + lane];
        const float x0 = xs[(rb + 0) * CC + c];   // broadcast reads
        const float x1 = xs[(rb + 1) * CC + c];
        const float x2v = xs[(rb + 2) * CC + c];
        const float x3 = xs[(rb + 3) * CC + c];
        a1[0] = fmaf(x0, w1v, a1[0]);  a2[0] = fmaf(x0, w2v, a2[0]);
        a1[1] = fmaf(x1, w1v, a1[1]);  a2[1] = fmaf(x1, w2v, a2[1]);
        a1[2] = fmaf(x2v, w1v, a1[2]); a2[2] = fmaf(x2v, w2v, a2[2]);
        a1[3] = fmaf(x3, w1v, a1[3]);  a2[3] = fmaf(x3, w2v, a2[3]);
    }
    const float K2 = 2.8853900817779268f;  // 2*log2(e)
#pragma unroll
    for (int rr = 0; rr < 4; ++rr) {
        const size_t r = (size_t)(r0 + rb + rr);
        e1p[r * CC + lane] = fast_exp2(fminf(a1[rr] * K2, 15.f));
        e2p[r * CC + lane] = fast_exp2(fminf(a2[rr] * K2, 15.f));
    }
}

// ---------------- Kernel 2: fused att + softmax -----------------------------
// paired reciprocal for one i-pair, one j (2 elements):
__device__ __forceinline__ void step2(float e1a, float e1b, float e2,
                                      float wc, float2& acc) {
    float da = fmaf(e1a, e2, 1.f);
    float db = fmaf(e1b, e2, 1.f);
    float r  = fast_rcp(da * db);
    float t  = wc * r;
    acc.x = fmaf(db, t, acc.x);   // wc / da
    acc.y = fmaf(da, t, acc.y);   // wc / db
}

__global__ __launch_bounds__(BLK, 4) void attn_kernel(
    const float* __restrict__ e1p, const float* __restrict__ e2p,
    const float* __restrict__ w3, float* __restrict__ out) {
    __shared__ float e1t[CC * TI];          // [c][i] transposed: 1 KB
    __shared__ float att_lds[TI * NN];      // 16 KB

    const int tid = threadIdx.x;
    const int bi  = blockIdx.x;             // 1024 blocks
    const int b   = bi >> 8;                // 256 blocks per batch
    const int i0  = (bi & 255) * TI;

    {   // stage e1 tile transposed (tid exactly covers CC*TI = 256)
        const int ii = tid >> 6, c = tid & 63;
        e1t[c * TI + ii] = e1p[(size_t)((b << 10) + i0 + ii) * CC + c];
    }
    __syncthreads();

    // w3 sum via uniform scalar loads
    const float4* __restrict__ w3q = (const float4*)w3;
    float sumw3 = 0.f;
#pragma unroll
    for (int q = 0; q < 16; ++q) {
        float4 t = w3q[q];
        sumw3 += (t.x + t.y) + (t.z + t.w);
    }

    const float* __restrict__ e2b = e2p + ((size_t)b << 10) * CC;
    const float4* __restrict__ rowA = (const float4*)(e2b + (size_t)(tid          ) * CC);
    const float4* __restrict__ rowB = (const float4*)(e2b + (size_t)(tid + 1 * BLK) * CC);
    const float4* __restrict__ rowC = (const float4*)(e2b + (size_t)(tid + 2 * BLK) * CC);
    const float4* __restrict__ rowD = (const float4*)(e2b + (size_t)(tid + 3 * BLK) * CC);
    const float4* e1t4 = (const float4*)e1t;   // [c] -> 4 i's (broadcast)

    float2 aA = {0.f,0.f}, bA = {0.f,0.f};   // j=tid:      i01, i23
    float2 aB = {0.f,0.f}, bB = {0.f,0.f};   // j=tid+256
    float2 aC = {0.f,0.f}, bC = {0.f,0.f};   // j=tid+512
    float2 aD = {0.f,0.f}, bD = {0.f,0.f};   // j=tid+768

    // FULLY UNROLLED: straight-line code — scheduler must keep loads in
    // flight across compute (can't sink into a backedge), budget 128 VGPR.
#pragma unroll
    for (int ct = 0; ct < 16; ++ct) {      // 16 quads of 4 c
        const float4 eA = rowA[ct];        // 4 independent VMEM loads
        const float4 eB = rowB[ct];
        const float4 eC = rowC[ct];
        const float4 eD = rowD[ct];
        const float4 wq = w3q[ct];         // uniform -> s_load (hoisted)

        const float4 e0 = e1t4[ct * 4 + 0];     // one ds_read_b128 ...
        step2(e0.x, e0.y, eA.x, wq.x, aA);      // ... feeds 8 step2
        step2(e0.z, e0.w, eA.x, wq.x, bA);
        step2(e0.x, e0.y, eB.x, wq.x, aB);
        step2(e0.z, e0.w, eB.x, wq.x, bB);
        step2(e0.x, e0.y, eC.x, wq.x, aC);
        step2(e0.z, e0.w, eC.x, wq.x, bC);
        step2(e0.x, e0.y, eD.x, wq.x, aD);
        step2(e0.z, e0.w, eD.x, wq.x, bD);

        const float4 e1v = e1t4[ct * 4 + 1];
        step2(e1v.x, e1v.y, eA.y, wq.y, aA);
        step2(e1v.z, e1v.w, eA.y, wq.y, bA);
        step2(e1v.x, e1v.y, eB.y, wq.y, aB);
        step2(e1v.z, e1v.w, eB.y, wq.y, bB);
        step2(e1v.x, e1v.y, eC.y, wq.y, aC);
        step2(e1v.z, e1v.w, eC.y, wq.y, bC);
        step2(e1v.x, e1v.y, eD.y, wq.y, aD);
        step2(e1v.z, e1v.w, eD.y, wq.y, bD);

        const float4 e2v = e1t4[ct * 4 + 2];
        step2(e2v.x, e2v.y, eA.z, wq.z, aA);
        step2(e2v.z, e2v.w, eA.z, wq.z, bA);
        step2(e2v.x, e2v.y, eB.z, wq.z, aB);
        step2(e2v.z, e2v.w, eB.z, wq.z, bB);
        step2(e2v.x, e2v.y, eC.z, wq.z, aC);
        step2(e2v.z, e2v.w, eC.z, wq.z, bC);
        step2(e2v.x, e2v.y, eD.z, wq.z, aD);
        step2(e2v.z, e2v.w, eD.z, wq.z, bD);

        const float4 e3v = e1t4[ct * 4 + 3];
        step2(e3v.x, e3v.y, eA.w, wq.w, aA);
        step2(e3v.z, e3v.w, eA.w, wq.w, bA);
        step2(e3v.x, e3v.y, eB.w, wq.w, aB);
        step2(e3v.z, e3v.w, eB.w, wq.w, bB);
        step2(e3v.x, e3v.y, eC.w, wq.w, aC);
        step2(e3v.z, e3v.w, eC.w, wq.w, bC);
        step2(e3v.x, e3v.y, eD.w, wq.w, aD);
        step2(e3v.z, e3v.w, eD.w, wq.w, bD);
    }

    {
        const int j0 = tid;
        att_lds[0 * NN + j0 + 0 * BLK] = fmaf(-2.f, aA.x, sumw3);
        att_lds[1 * NN + j0 + 0 * BLK] = fmaf(-2.f, aA.y, sumw3);
        att_lds[2 * NN + j0 + 0 * BLK] = fmaf(-2.f, bA.x, sumw3);
        att_lds[3 * NN + j0 + 0 * BLK] = fmaf(-2.f, bA.y, sumw3);
        att_lds[0 * NN + j0 + 1 * BLK] = fmaf(-2.f, aB.x, sumw3);
        att_lds[1 * NN + j0 + 1 * BLK] = fmaf(-2.f, aB.y, sumw3);
        att_lds[2 * NN + j0 + 1 * BLK] = fmaf(-2.f, bB.x, sumw3);
        att_lds[3 * NN + j0 + 1 * BLK] = fmaf(-2.f, bB.y, sumw3);
        att_lds[0 * NN + j0 + 2 * BLK] = fmaf(-2.f, aC.x, sumw3);
        att_lds[1 * NN + j0 + 2 * BLK] = fmaf(-2.f, aC.y, sumw3);
        att_lds[2 * NN + j0 + 2 * BLK] = fmaf(-2.f, bC.x, sumw3);
        att_lds[3 * NN + j0 + 2 * BLK] = fmaf(-2.f, bC.y, sumw3);
        att_lds[0 * NN + j0 + 3 * BLK] = fmaf(-2.f, aD.x, sumw3);
        att_lds[1 * NN + j0 + 3 * BLK] = fmaf(-2.f, aD.y, sumw3);
        att_lds[2 * NN + j0 + 3 * BLK] = fmaf(-2.f, bD.x, sumw3);
        att_lds[3 * NN + j0 + 3 * BLK] = fmaf(-2.f, bD.y, sumw3);
    }
    __syncthreads();

    // epilogue: wave w softmaxes row i0+w over j (4 waves = TI rows)
    {
        const int w    = tid >> 6;
        const int lane = tid & 63;
        float v[16];
        float m = -3.4e38f;
#pragma unroll
        for (int k = 0; k < 16; ++k) {
            v[k] = att_lds[w * NN + k * 64 + lane];
            m = fmaxf(m, v[k]);
        }
#pragma unroll
        for (int off = 32; off >= 1; off >>= 1)
            m = fmaxf(m, __shfl_xor(m, off));
        const float L2E = 1.4426950408889634f;
        float s = 0.f;
#pragma unroll
        for (int k = 0; k < 16; ++k) {
            v[k] = fast_exp2((v[k] - m) * L2E);
            s += v[k];
        }
#pragma unroll
        for (int off = 32; off >= 1; off >>= 1)
            s += __shfl_xor(s, off);
        const float rs = fast_rcp(s);
        float* __restrict__ orow = out + (((size_t)(b << 10) + (i0 + w)) << 10);
#pragma unroll
        for (int k = 0; k < 16; ++k) orow[k * 64 + lane] = v[k] * rs;
    }
}

extern "C" void kernel_launch(void* const* d_in, const int* in_sizes, int n_in,
                              void* d_out, int out_size, void* d_ws, size_t ws_size,
                              hipStream_t stream) {
    const float* x  = (const float*)d_in[0];
    const float* W1 = (const float*)d_in[1];
    const float* W2 = (const float*)d_in[2];
    const float* w3 = (const float*)d_in[3];
    float* outp = (float*)d_out;

    float* e1p = (float*)d_ws;                       // 4096*64 fp32 = 1 MB
    float* e2p = e1p + (size_t)BATCH * NN * CC;      // second 1 MB

    proj_kernel<<<dim3(BATCH * NN / PROWS), dim3(256), 0, stream>>>(x, W1, W2, e1p, e2p);
    attn_kernel<<<dim3(BATCH * NN / TI), dim3(BLK), 0, stream>>>(e1p, e2p, w3, outp);
}